// Round 1
// baseline (179.384 us; speedup 1.0000x reference)
//
#include <hip/hip_runtime.h>

#define F_BINS 257
#define T_STEPS 65536
#define N_ACT 256

// ws layout: bytes [0..31]  : unsigned mask[8]   (selected-action bitmask)
//            bytes [32..39] : double S_big       (sum of x_out^2)
//            bytes [40..47] : double S_corr      (correction term)

// ---------------------------------------------------------------------------
// Kernel B: proj = x_source^T @ G  (fp32), clean_sum, per-t argmin -> action
// bitmask. Block = 256 threads (4 waves). Each block covers 128 t's; wave w
// owns actions [w*64, w*64+64). Lane l handles t0+l and t0+64+l (float2 acc).
// ---------------------------------------------------------------------------
__global__ __launch_bounds__(256, 2) void k_gemm_argmin(
    const float* __restrict__ xs, const float* __restrict__ xc,
    const float* __restrict__ G, unsigned* __restrict__ gmask) {
  const int tid  = threadIdx.x;
  const int lane = tid & 63;
  const int wv   = __builtin_amdgcn_readfirstlane(tid >> 6);  // force SGPR
  const int t0   = blockIdx.x * 128;
  const int t1   = t0 + lane;
  const int t2   = t1 + 64;

  float2 acc[64];
#pragma unroll
  for (int j = 0; j < 64; ++j) acc[j] = make_float2(0.f, 0.f);
  float cl1 = 0.f, cl2 = 0.f;

  const float* Gbase = G + wv * 64;  // wave-uniform
  for (int f = 0; f < F_BINS; ++f) {
    const int rowoff = f * T_STEPS;
    const float x1 = xs[rowoff + t1];
    const float x2 = xs[rowoff + t2];
    cl1 += xc[rowoff + t1];
    cl2 += xc[rowoff + t2];
    const float4* Gr = (const float4*)(Gbase + f * N_ACT);  // wave-uniform ptr
#pragma unroll
    for (int q = 0; q < 16; ++q) {
      const float4 g = Gr[q];
      acc[4*q+0].x = fmaf(x1, g.x, acc[4*q+0].x);
      acc[4*q+0].y = fmaf(x2, g.x, acc[4*q+0].y);
      acc[4*q+1].x = fmaf(x1, g.y, acc[4*q+1].x);
      acc[4*q+1].y = fmaf(x2, g.y, acc[4*q+1].y);
      acc[4*q+2].x = fmaf(x1, g.z, acc[4*q+2].x);
      acc[4*q+2].y = fmaf(x2, g.z, acc[4*q+2].y);
      acc[4*q+3].x = fmaf(x1, g.w, acc[4*q+3].x);
      acc[4*q+3].y = fmaf(x2, g.w, acc[4*q+3].y);
    }
  }

  // per-thread argmin over this wave's 64 actions (first-min tie-break:
  // ascending j, strict less)
  float bv1 = cl1 - acc[0].x; int bi1 = wv * 64;
  float bv2 = cl2 - acc[0].y; int bi2 = wv * 64;
#pragma unroll
  for (int j = 1; j < 64; ++j) {
    const float s1 = cl1 - acc[j].x;
    const float s2 = cl2 - acc[j].y;
    if (s1 < bv1) { bv1 = s1; bi1 = wv * 64 + j; }
    if (s2 < bv2) { bv2 = s2; bi2 = wv * 64 + j; }
  }

  __shared__ float    s_bv[4][128];
  __shared__ int      s_bi[4][128];
  __shared__ unsigned lmask[8];
  s_bv[wv][lane]      = bv1; s_bi[wv][lane]      = bi1;
  s_bv[wv][lane + 64] = bv2; s_bi[wv][lane + 64] = bi2;
  if (tid < 8) lmask[tid] = 0u;
  __syncthreads();

  if (tid < 128) {
    // cross-wave reduce; ascending wave = ascending action index, strict less
    float bv = s_bv[0][tid]; int bi = s_bi[0][tid];
#pragma unroll
    for (int w = 1; w < 4; ++w) {
      const float v = s_bv[w][tid];
      if (v < bv) { bv = v; bi = s_bi[w][tid]; }
    }
    atomicOr(&lmask[bi >> 5], 1u << (bi & 31));
  }
  __syncthreads();
  if (tid < 8 && lmask[tid]) atomicOr(&gmask[tid], lmask[tid]);
}

// ---------------------------------------------------------------------------
// Kernel D: S_big = sum over all elements of x_out^2 (grid-stride float4)
// ---------------------------------------------------------------------------
__global__ __launch_bounds__(256) void k_sumsq(const float4* __restrict__ xo4,
                                               double* __restrict__ S) {
  const int n4 = (F_BINS * T_STEPS) / 4;
  double acc = 0.0;
  for (int i = blockIdx.x * blockDim.x + threadIdx.x; i < n4;
       i += gridDim.x * blockDim.x) {
    const float4 v = xo4[i];
    acc += (double)fmaf(v.x, v.x, v.y * v.y) + (double)fmaf(v.z, v.z, v.w * v.w);
  }
#pragma unroll
  for (int off = 32; off; off >>= 1) acc += __shfl_down(acc, off, 64);
  __shared__ double s[4];
  if ((threadIdx.x & 63) == 0) s[threadIdx.x >> 6] = acc;
  __syncthreads();
  if (threadIdx.x == 0) atomicAdd(S, s[0] + s[1] + s[2] + s[3]);
}

// ---------------------------------------------------------------------------
// Kernel C: correction for selected columns t = a < 256:
//   S_corr += sel[a] * ((G*xs)^2 - 2*G*xs*xo)   summed over f
// One block per f, thread = action a (coalesced across a).
// ---------------------------------------------------------------------------
__global__ __launch_bounds__(256) void k_corr(
    const float* __restrict__ xs, const float* __restrict__ xo,
    const float* __restrict__ G, const unsigned* __restrict__ gmask,
    double* __restrict__ S) {
  const int f = blockIdx.x;
  const int a = threadIdx.x;
  const bool sel = (gmask[a >> 5] >> (a & 31)) & 1u;
  const float g   = G[f * N_ACT + a];
  const float xsv = xs[f * T_STEPS + a];
  const float xov = xo[f * T_STEPS + a];
  const float gx  = g * xsv;
  double acc = sel ? (double)(gx * (gx - 2.f * xov)) : 0.0;
#pragma unroll
  for (int off = 32; off; off >>= 1) acc += __shfl_down(acc, off, 64);
  __shared__ double s[4];
  if ((threadIdx.x & 63) == 0) s[threadIdx.x >> 6] = acc;
  __syncthreads();
  if (threadIdx.x == 0) atomicAdd(S, s[0] + s[1] + s[2] + s[3]);
}

// ---------------------------------------------------------------------------
// Kernel E: finalize loss = (S_big + S_corr) / (F*T)
// ---------------------------------------------------------------------------
__global__ void k_final(const double* __restrict__ Sb,
                        const double* __restrict__ Sc,
                        float* __restrict__ out) {
  out[0] = (float)((*Sb + *Sc) / ((double)F_BINS * (double)T_STEPS));
}

extern "C" void kernel_launch(void* const* d_in, const int* in_sizes, int n_in,
                              void* d_out, int out_size, void* d_ws, size_t ws_size,
                              hipStream_t stream) {
  const float* x_out    = (const float*)d_in[0];
  const float* x_source = (const float*)d_in[1];
  const float* x_clean  = (const float*)d_in[2];
  const float* G        = (const float*)d_in[3];

  unsigned* mask = (unsigned*)d_ws;
  double*   Sb   = (double*)((char*)d_ws + 32);
  double*   Sc   = (double*)((char*)d_ws + 40);

  hipMemsetAsync(d_ws, 0, 64, stream);
  k_gemm_argmin<<<T_STEPS / 128, 256, 0, stream>>>(x_source, x_clean, G, mask);
  k_sumsq<<<2048, 256, 0, stream>>>((const float4*)x_out, Sb);
  k_corr<<<F_BINS, 256, 0, stream>>>(x_source, x_out, G, mask, Sc);
  k_final<<<1, 1, 0, stream>>>(Sb, Sc, (float*)d_out);
}

// Round 2
// 142.535 us; speedup vs baseline: 1.2585x; 1.2585x over previous
//
#include <hip/hip_runtime.h>

#define F_BINS  257
#define T_STEPS 65536
#define N_ACT   256
#define GT_PITCH 296   // bf16 elems/row of Gt; 592 B = 37*16 -> frags 16B-aligned
#define NBLK    512    // k_fused blocks, 128 t-columns each

typedef float f32x4 __attribute__((ext_vector_type(4)));
typedef short s16x8 __attribute__((ext_vector_type(8)));
typedef unsigned u32x4 __attribute__((ext_vector_type(4)));

// ws layout:
//   [0]      double Sc                      (correction sum; memset each call)
//   [4096]   double partial[NBLK]           (per-block sum of x_out^2)
//   [16384]  unsigned maskp[NBLK*8]         (per-block selected-action bitmask)
//   [65536]  ushort Gt[256*GT_PITCH]        (G transposed -> [a][f] bf16, zero-pad f>=257)

__device__ __forceinline__ unsigned short f2bf_rne(float x) {
  unsigned u = __builtin_bit_cast(unsigned, x);
  return (unsigned short)((u + 0x7FFFu + ((u >> 16) & 1u)) >> 16);
}

// pack bf16(hi)<<16 | bf16(lo) by truncation: one v_perm_b32
__device__ __forceinline__ unsigned pack_bf(float hi, float lo) {
  return __builtin_amdgcn_perm(__builtin_bit_cast(unsigned, hi),
                               __builtin_bit_cast(unsigned, lo), 0x07060302u);
}

// ---------------------------------------------------------------------------
// G [257][256] fp32  ->  Gt [256][GT_PITCH] bf16 (transposed, K zero-padded)
// ---------------------------------------------------------------------------
__global__ __launch_bounds__(256) void k_prep(const float* __restrict__ G,
                                              unsigned short* __restrict__ Gt) {
  __shared__ float tile[16][17];
  const int tx = threadIdx.x, ty = threadIdx.y;
  const int a0 = blockIdx.x * 16, f0 = blockIdx.y * 16;
  const int f = f0 + ty;
  tile[ty][tx] = (f < F_BINS) ? G[f * N_ACT + (a0 + tx)] : 0.f;
  __syncthreads();
  const int fw = f0 + tx;
  if (fw < GT_PITCH) Gt[(a0 + ty) * GT_PITCH + fw] = f2bf_rne(tile[tx][ty]);
}

// ---------------------------------------------------------------------------
// Fused: proj = x_s^T G via bf16 MFMA, per-t argmax -> per-block action mask;
// plus per-block sum of x_out^2 over the same 128 t-columns.
// Block = 256 thr (4 waves); wave = 32 rows (2 MFMA row-tiles) x 256 actions.
// ---------------------------------------------------------------------------
__global__ __launch_bounds__(256) void k_fused(
    const float* __restrict__ xs, const float* __restrict__ xo,
    const unsigned short* __restrict__ Gt,
    unsigned* __restrict__ maskp, double* __restrict__ partial) {
  const int tid  = threadIdx.x;
  const int lane = tid & 63;
  const int wv   = tid >> 6;
  const int g    = lane >> 4;   // k-block within fragment
  const int r16  = lane & 15;   // row (A) / col (B) within tile
  const int t0   = blockIdx.x * 128;
  const int trow0 = t0 + wv * 32 + r16;
  const int trow1 = trow0 + 16;

  f32x4 acc0[16], acc1[16];
#pragma unroll
  for (int n = 0; n < 16; ++n) {
    acc0[n] = (f32x4){0.f, 0.f, 0.f, 0.f};
    acc1[n] = (f32x4){0.f, 0.f, 0.f, 0.f};
  }

  const unsigned short* gb = Gt + r16 * GT_PITCH + 8 * g;

#pragma unroll
  for (int kk = 0; kk < 9; ++kk) {
    const int fb = kk * 32;
    float va0[8], va1[8];
#pragma unroll
    for (int j = 0; j < 8; ++j) {
      const int f = fb + 8 * g + j;
      va0[j] = 0.f; va1[j] = 0.f;
      if (f < F_BINS) {            // compile-time true for kk < 8
        va0[j] = xs[f * T_STEPS + trow0];
        va1[j] = xs[f * T_STEPS + trow1];
      }
    }
    const s16x8 af0 = __builtin_bit_cast(s16x8, (u32x4){
        pack_bf(va0[1], va0[0]), pack_bf(va0[3], va0[2]),
        pack_bf(va0[5], va0[4]), pack_bf(va0[7], va0[6])});
    const s16x8 af1 = __builtin_bit_cast(s16x8, (u32x4){
        pack_bf(va1[1], va1[0]), pack_bf(va1[3], va1[2]),
        pack_bf(va1[5], va1[4]), pack_bf(va1[7], va1[6])});
#pragma unroll
    for (int n = 0; n < 16; ++n) {
      const s16x8 bf = *(const s16x8*)(gb + n * 16 * GT_PITCH + fb);
      acc0[n] = __builtin_amdgcn_mfma_f32_16x16x32_bf16(af0, bf, acc0[n], 0, 0, 0);
      acc1[n] = __builtin_amdgcn_mfma_f32_16x16x32_bf16(af1, bf, acc1[n], 0, 0, 0);
    }
  }

  // ---- per-row argmax over 256 actions ----
  // D layout: row = g*4 + q (within tile), col = 16n + r16
  float bv0[4], bv1[4]; int bc0[4], bc1[4];
#pragma unroll
  for (int q = 0; q < 4; ++q) {
    bv0[q] = acc0[0][q]; bc0[q] = r16;
    bv1[q] = acc1[0][q]; bc1[q] = r16;
  }
#pragma unroll
  for (int n = 1; n < 16; ++n) {
    const int c = 16 * n + r16;
#pragma unroll
    for (int q = 0; q < 4; ++q) {
      if (acc0[n][q] > bv0[q]) { bv0[q] = acc0[n][q]; bc0[q] = c; }
      if (acc1[n][q] > bv1[q]) { bv1[q] = acc1[n][q]; bc1[q] = c; }
    }
  }
#pragma unroll
  for (int m = 1; m <= 8; m <<= 1) {
#pragma unroll
    for (int q = 0; q < 4; ++q) {
      float ov; int oc;
      ov = __shfl_xor(bv0[q], m); oc = __shfl_xor(bc0[q], m);
      if (ov > bv0[q] || (ov == bv0[q] && oc < bc0[q])) { bv0[q] = ov; bc0[q] = oc; }
      ov = __shfl_xor(bv1[q], m); oc = __shfl_xor(bc1[q], m);
      if (ov > bv1[q] || (ov == bv1[q] && oc < bc1[q])) { bv1[q] = ov; bc1[q] = oc; }
    }
  }

  __shared__ unsigned lmask[8];
  if (tid < 8) lmask[tid] = 0u;
  __syncthreads();
  if (r16 == 0) {
#pragma unroll
    for (int q = 0; q < 4; ++q) {
      atomicOr(&lmask[bc0[q] >> 5], 1u << (bc0[q] & 31));
      atomicOr(&lmask[bc1[q] >> 5], 1u << (bc1[q] & 31));
    }
  }
  __syncthreads();
  if (tid < 8) maskp[blockIdx.x * 8 + tid] = lmask[tid];

  // ---- fused sum of x_out^2 over this block's 128 t-columns ----
  float s = 0.f;
  for (int f = wv; f < F_BINS; f += 4) {
    const float v0 = xo[f * T_STEPS + t0 + lane];
    const float v1 = xo[f * T_STEPS + t0 + 64 + lane];
    s = fmaf(v0, v0, s);
    s = fmaf(v1, v1, s);
  }
  double ds = (double)s;
#pragma unroll
  for (int off = 32; off; off >>= 1) ds += __shfl_down(ds, off);
  __shared__ double sd[4];
  if (lane == 0) sd[wv] = ds;
  __syncthreads();
  if (tid == 0) partial[blockIdx.x] = sd[0] + sd[1] + sd[2] + sd[3];
}

// ---------------------------------------------------------------------------
// OR-reduce per-block masks, then correction for selected columns t = a:
//   Sc += sum_f (G*xs)^2 - 2*(G*xs)*xo   at column a, for selected a
// ---------------------------------------------------------------------------
__global__ __launch_bounds__(256) void k_corr(
    const float* __restrict__ xs, const float* __restrict__ xo,
    const float* __restrict__ G, const unsigned* __restrict__ maskp,
    double* __restrict__ Sc) {
  __shared__ unsigned m8[8];
  const int tid = threadIdx.x;
  if (tid < 8) m8[tid] = 0u;
  __syncthreads();
  unsigned m = 0;
  for (int b = tid >> 3; b < NBLK; b += 32) m |= maskp[b * 8 + (tid & 7)];
  atomicOr(&m8[tid & 7], m);
  __syncthreads();
  const int f = blockIdx.x;
  const int a = tid;
  const bool sel = (m8[a >> 5] >> (a & 31)) & 1u;
  const float gv  = G[f * N_ACT + a];
  const float xsv = xs[f * T_STEPS + a];
  const float xov = xo[f * T_STEPS + a];
  const float gx  = gv * xsv;
  double acc = sel ? (double)(gx * (gx - 2.f * xov)) : 0.0;
#pragma unroll
  for (int off = 32; off; off >>= 1) acc += __shfl_down(acc, off);
  __shared__ double sdc[4];
  if ((tid & 63) == 0) sdc[tid >> 6] = acc;
  __syncthreads();
  if (tid == 0) atomicAdd(Sc, sdc[0] + sdc[1] + sdc[2] + sdc[3]);
}

__global__ void k_final(const double* __restrict__ partial,
                        const double* __restrict__ Sc,
                        float* __restrict__ out) {
  const int tid = threadIdx.x;
  double s = 0.0;
  for (int i = tid; i < NBLK; i += 256) s += partial[i];
#pragma unroll
  for (int off = 32; off; off >>= 1) s += __shfl_down(s, off);
  __shared__ double sd[4];
  if ((tid & 63) == 0) sd[tid >> 6] = s;
  __syncthreads();
  if (tid == 0)
    out[0] = (float)((sd[0] + sd[1] + sd[2] + sd[3] + Sc[0]) /
                     ((double)F_BINS * (double)T_STEPS));
}

extern "C" void kernel_launch(void* const* d_in, const int* in_sizes, int n_in,
                              void* d_out, int out_size, void* d_ws, size_t ws_size,
                              hipStream_t stream) {
  const float* x_out    = (const float*)d_in[0];
  const float* x_source = (const float*)d_in[1];
  // d_in[2] (x_clean) is mathematically dead: argmin_a(clean_sum - proj) == argmax_a proj
  const float* G        = (const float*)d_in[3];

  char* ws = (char*)d_ws;
  double*         Sc      = (double*)ws;
  double*         partial = (double*)(ws + 4096);
  unsigned*       maskp   = (unsigned*)(ws + 16384);
  unsigned short* Gt      = (unsigned short*)(ws + 65536);

  hipMemsetAsync(d_ws, 0, 64, stream);
  k_prep <<<dim3(16, 19), dim3(16, 16), 0, stream>>>(G, Gt);
  k_fused<<<NBLK, 256, 0, stream>>>(x_source, x_out, Gt, maskp, partial);
  k_corr <<<F_BINS, 256, 0, stream>>>(x_source, x_out, G, maskp, Sc);
  k_final<<<1, 256, 0, stream>>>(partial, Sc, (float*)d_out);
}

// Round 3
// 74.466 us; speedup vs baseline: 2.4089x; 1.9141x over previous
//
#include <hip/hip_runtime.h>

#define F_BINS  257
#define T_STEPS 65536
#define N_ACT   256
#define GT_PITCH 296   // bf16 elems/row of Gt; 592 B = 37*16 -> frags 16B-aligned
#define TM      64     // t-columns per block
#define NBLK    1024   // T_STEPS / TM
#define XO_CHUNK 4112  // (257*65536/4) float4 / 1024 blocks, exact

typedef float f32x4 __attribute__((ext_vector_type(4)));
typedef short s16x8 __attribute__((ext_vector_type(8)));
typedef unsigned u32x4 __attribute__((ext_vector_type(4)));

// ws layout:
//   [0]      double Sc                      (correction sum; memset each call)
//   [4096]   double partial[NBLK]           (per-block sum of x_out^2)
//   [16384]  unsigned maskp[NBLK*8]         (per-block selected-action bitmask)
//   [65536]  ushort Gt[256*GT_PITCH]        (G transposed -> [a][f] bf16, zero-pad f>=257)

__device__ __forceinline__ unsigned short f2bf_rne(float x) {
  unsigned u = __builtin_bit_cast(unsigned, x);
  return (unsigned short)((u + 0x7FFFu + ((u >> 16) & 1u)) >> 16);
}

// pack bf16(hi)<<16 | bf16(lo) by truncation: one v_perm_b32
__device__ __forceinline__ unsigned pack_bf(float hi, float lo) {
  return __builtin_amdgcn_perm(__builtin_bit_cast(unsigned, hi),
                               __builtin_bit_cast(unsigned, lo), 0x07060302u);
}

// ---------------------------------------------------------------------------
// G [257][256] fp32  ->  Gt [256][GT_PITCH] bf16 (transposed, K zero-padded)
// ---------------------------------------------------------------------------
__global__ __launch_bounds__(256) void k_prep(const float* __restrict__ G,
                                              unsigned short* __restrict__ Gt) {
  __shared__ float tile[16][17];
  const int tx = threadIdx.x, ty = threadIdx.y;
  const int a0 = blockIdx.x * 16, f0 = blockIdx.y * 16;
  const int f = f0 + ty;
  tile[ty][tx] = (f < F_BINS) ? G[f * N_ACT + (a0 + tx)] : 0.f;
  __syncthreads();
  const int fw = f0 + tx;
  if (fw < GT_PITCH) Gt[(a0 + ty) * GT_PITCH + fw] = f2bf_rne(tile[tx][ty]);
}

// ---------------------------------------------------------------------------
// Fused: proj = x_s^T G via bf16 MFMA (LDS-staged A, double-buffered,
// counted-vmcnt), per-t argmax -> per-block action mask; plus per-block
// contiguous sum of x_out^2.
// Block = 256 thr (4 waves); wave owns 16 t-rows x 256 actions.
// ---------------------------------------------------------------------------
__global__ __launch_bounds__(256, 2) void k_fused(
    const float* __restrict__ xs, const float* __restrict__ xo,
    const unsigned short* __restrict__ Gt,
    unsigned* __restrict__ maskp, double* __restrict__ partial) {
  const int tid  = threadIdx.x;
  const int lane = tid & 63;
  const int wv   = tid >> 6;
  const int g    = lane >> 4;   // k-group within fragment
  const int r16  = lane & 15;   // A-row (t) / B-col (action) within tile
  const int t0   = blockIdx.x * TM;

  __shared__ float tile[2][32 * TM];  // 2 x 8KB, [f 0..31][t 0..63]
  __shared__ unsigned lmask[8];
  __shared__ double sd[4];
  if (tid < 8) lmask[tid] = 0u;

  f32x4 acc[16];
#pragma unroll
  for (int n = 0; n < 16; ++n) acc[n] = (f32x4){0.f, 0.f, 0.f, 0.f};

  // ---- stage helper: rows f = kkbase..kkbase+31 (clamped to 256) ----
  // wave wv stages rows 8wv..8wv+7; per instr: 4 rows x 64 cols (1KB), linear LDS.
#define STAGE(buf, kkbase)                                                   \
  {                                                                          \
    _Pragma("unroll") for (int i = 0; i < 2; ++i) {                          \
      int r = 8 * wv + 4 * i + (lane >> 4);                                  \
      int f = (kkbase) + r;                                                  \
      f = f > 256 ? 256 : f; /* B rows >=257 are zero, A garbage harmless */ \
      const float* src = xs + (size_t)f * T_STEPS + t0 + (lane & 15) * 4;    \
      float* dst = &tile[buf][(8 * wv + 4 * i) * TM]; /* wave-uniform */     \
      __builtin_amdgcn_global_load_lds(                                      \
          (const __attribute__((address_space(1))) unsigned*)src,            \
          (__attribute__((address_space(3))) unsigned*)dst, 16, 0, 0);       \
    }                                                                        \
  }

  const int tbase = wv * 16 + r16;               // A ds_read column
  const unsigned short* gb0 = Gt + r16 * GT_PITCH + 8 * g;

  STAGE(0, 0);
#pragma unroll
  for (int kk = 0; kk < 9; ++kk) {
    const int cur = kk & 1;
    if (kk < 8) {
      STAGE(cur ^ 1, (kk + 1) * 32);
      asm volatile("s_waitcnt vmcnt(2)" ::: "memory");  // current buf staged
    } else {
      asm volatile("s_waitcnt vmcnt(0)" ::: "memory");
    }
    __builtin_amdgcn_s_barrier();   // raw: don't drain next-stage loads

    float va[8];
#pragma unroll
    for (int j = 0; j < 8; ++j)
      va[j] = tile[cur][(8 * g + j) * TM + tbase];
    const s16x8 af = __builtin_bit_cast(s16x8, (u32x4){
        pack_bf(va[1], va[0]), pack_bf(va[3], va[2]),
        pack_bf(va[5], va[4]), pack_bf(va[7], va[6])});
    const unsigned short* gb = gb0 + kk * 32;
#pragma unroll
    for (int n = 0; n < 16; ++n) {
      const s16x8 bf = *(const s16x8*)(gb + n * 16 * GT_PITCH);
      acc[n] = __builtin_amdgcn_mfma_f32_16x16x32_bf16(af, bf, acc[n], 0, 0, 0);
    }
    __builtin_amdgcn_s_barrier();   // all waves done reading before overwrite
  }
#undef STAGE

  // ---- per-row argmax over 256 actions ----
  // D layout: row = 4g + q (t = t0 + wv*16 + row), col = 16n + r16
  float bv[4]; int bc[4];
#pragma unroll
  for (int q = 0; q < 4; ++q) { bv[q] = acc[0][q]; bc[q] = r16; }
#pragma unroll
  for (int n = 1; n < 16; ++n) {
    const int c = 16 * n + r16;
#pragma unroll
    for (int q = 0; q < 4; ++q)
      if (acc[n][q] > bv[q]) { bv[q] = acc[n][q]; bc[q] = c; }
  }
#pragma unroll
  for (int m = 1; m <= 8; m <<= 1) {
#pragma unroll
    for (int q = 0; q < 4; ++q) {
      const float ov = __shfl_xor(bv[q], m);
      const int   oc = __shfl_xor(bc[q], m);
      if (ov > bv[q] || (ov == bv[q] && oc < bc[q])) { bv[q] = ov; bc[q] = oc; }
    }
  }
  __syncthreads();
  if (r16 == 0) {
#pragma unroll
    for (int q = 0; q < 4; ++q)
      atomicOr(&lmask[bc[q] >> 5], 1u << (bc[q] & 31));
  }
  __syncthreads();
  if (tid < 8) maskp[blockIdx.x * 8 + tid] = lmask[tid];

  // ---- per-block contiguous sum of x_out^2 (coalesced float4) ----
  const float4* xo4 = (const float4*)xo;
  const int base = blockIdx.x * XO_CHUNK;
  double ds = 0.0;
  for (int i = tid; i < XO_CHUNK; i += 256) {
    const float4 v = xo4[base + i];
    ds += (double)fmaf(v.x, v.x, v.y * v.y) + (double)fmaf(v.z, v.z, v.w * v.w);
  }
#pragma unroll
  for (int off = 32; off; off >>= 1) ds += __shfl_down(ds, off);
  if (lane == 0) sd[wv] = ds;
  __syncthreads();
  if (tid == 0) partial[blockIdx.x] = sd[0] + sd[1] + sd[2] + sd[3];
}

// ---------------------------------------------------------------------------
// OR-reduce per-block masks, then correction for selected columns t = a:
//   Sc += sum_f (G*xs)^2 - 2*(G*xs)*xo   at column a, for selected a
// ---------------------------------------------------------------------------
__global__ __launch_bounds__(256) void k_corr(
    const float* __restrict__ xs, const float* __restrict__ xo,
    const float* __restrict__ G, const unsigned* __restrict__ maskp,
    double* __restrict__ Sc) {
  __shared__ unsigned m8[8];
  const int tid = threadIdx.x;
  if (tid < 8) m8[tid] = 0u;
  __syncthreads();
  unsigned m = 0;
  for (int b = tid >> 3; b < NBLK; b += 32) m |= maskp[b * 8 + (tid & 7)];
  atomicOr(&m8[tid & 7], m);
  __syncthreads();
  const int f = blockIdx.x;
  const int a = tid;
  const bool sel = (m8[a >> 5] >> (a & 31)) & 1u;
  const float gv  = G[f * N_ACT + a];
  const float xsv = xs[f * T_STEPS + a];
  const float xov = xo[f * T_STEPS + a];
  const float gx  = gv * xsv;
  double acc = sel ? (double)(gx * (gx - 2.f * xov)) : 0.0;
#pragma unroll
  for (int off = 32; off; off >>= 1) acc += __shfl_down(acc, off);
  __shared__ double sdc[4];
  if ((tid & 63) == 0) sdc[tid >> 6] = acc;
  __syncthreads();
  if (tid == 0) atomicAdd(Sc, sdc[0] + sdc[1] + sdc[2] + sdc[3]);
}

__global__ void k_final(const double* __restrict__ partial,
                        const double* __restrict__ Sc,
                        float* __restrict__ out) {
  const int tid = threadIdx.x;
  double s = 0.0;
  for (int i = tid; i < NBLK; i += 256) s += partial[i];
#pragma unroll
  for (int off = 32; off; off >>= 1) s += __shfl_down(s, off);
  __shared__ double sd[4];
  if ((tid & 63) == 0) sd[tid >> 6] = s;
  __syncthreads();
  if (tid == 0)
    out[0] = (float)((sd[0] + sd[1] + sd[2] + sd[3] + Sc[0]) /
                     ((double)F_BINS * (double)T_STEPS));
}

extern "C" void kernel_launch(void* const* d_in, const int* in_sizes, int n_in,
                              void* d_out, int out_size, void* d_ws, size_t ws_size,
                              hipStream_t stream) {
  const float* x_out    = (const float*)d_in[0];
  const float* x_source = (const float*)d_in[1];
  // d_in[2] (x_clean) is mathematically dead: argmin_a(clean_sum - proj) == argmax_a proj
  const float* G        = (const float*)d_in[3];

  char* ws = (char*)d_ws;
  double*         Sc      = (double*)ws;
  double*         partial = (double*)(ws + 4096);
  unsigned*       maskp   = (unsigned*)(ws + 16384);
  unsigned short* Gt      = (unsigned short*)(ws + 65536);

  hipMemsetAsync(d_ws, 0, 64, stream);
  k_prep <<<dim3(16, 19), dim3(16, 16), 0, stream>>>(G, Gt);
  k_fused<<<NBLK, 256, 0, stream>>>(x_source, x_out, Gt, maskp, partial);
  k_corr <<<F_BINS, 256, 0, stream>>>(x_source, x_out, G, maskp, Sc);
  k_final<<<1, 256, 0, stream>>>(partial, Sc, (float*)d_out);
}

// Round 4
// 60.677 us; speedup vs baseline: 2.9564x; 1.2273x over previous
//
#include <hip/hip_runtime.h>

#define F_BINS  257
#define T_STEPS 65536
#define N_ACT   256
#define GT_PITCH 296   // bf16 elems/row of Gt; 592 B = 37*16 -> frags 16B-aligned
#define TM      64     // t-columns per block
#define NBLK    1024   // T_STEPS / TM
#define XO_CHUNK 4112  // (257*65536/4) float4 / 1024 blocks, exact

typedef float f32x4 __attribute__((ext_vector_type(4)));
typedef short s16x8 __attribute__((ext_vector_type(8)));
typedef unsigned u32x4 __attribute__((ext_vector_type(4)));

// ws layout:
//   [0]      double Sc        (correction sum)
//   [8]      double Sb        (sum of x_out^2)
//   [16384]  unsigned maskp[NBLK*8]
//   [65536]  ushort Gt[256*GT_PITCH]   (G^T bf16, zero-pad f>=257)

__device__ __forceinline__ unsigned short f2bf_rne(float x) {
  unsigned u = __builtin_bit_cast(unsigned, x);
  return (unsigned short)((u + 0x7FFFu + ((u >> 16) & 1u)) >> 16);
}
__device__ __forceinline__ unsigned pack_bf(float hi, float lo) {
  return __builtin_amdgcn_perm(__builtin_bit_cast(unsigned, hi),
                               __builtin_bit_cast(unsigned, lo), 0x07060302u);
}

// ---------------------------------------------------------------------------
__global__ __launch_bounds__(256) void k_prep(const float* __restrict__ G,
                                              unsigned short* __restrict__ Gt) {
  __shared__ float tile[16][17];
  const int tx = threadIdx.x, ty = threadIdx.y;
  const int a0 = blockIdx.x * 16, f0 = blockIdx.y * 16;
  const int f = f0 + ty;
  tile[ty][tx] = (f < F_BINS) ? G[f * N_ACT + (a0 + tx)] : 0.f;
  __syncthreads();
  const int fw = f0 + tx;
  if (fw < GT_PITCH) Gt[(a0 + ty) * GT_PITCH + fw] = f2bf_rne(tile[tx][ty]);
}

// ---------------------------------------------------------------------------
// GEMM+argmax+xo^2. A = direct global->reg (prefetch depth 2).
// B = Gt slices via global_load_lds, 3-buffer ring, counted vmcnt (safe -8).
// Wave wv owns t-rows [t0+16wv, +16); all 256 actions per wave.
// ---------------------------------------------------------------------------
__global__ __launch_bounds__(256, 3) void k_gemm(
    const float* __restrict__ xs, const float* __restrict__ xo,
    const unsigned short* __restrict__ Gt,
    unsigned* __restrict__ maskp, double* __restrict__ Sb) {
  const int tid  = threadIdx.x;
  const int lane = tid & 63;
  const int wv   = tid >> 6;
  const int g    = lane >> 4;
  const int r16  = lane & 15;
  const int t0   = blockIdx.x * TM;
  const int trow = t0 + wv * 16 + r16;

  __shared__ __align__(16) unsigned short Bb[3][256][32];  // [buf][action][32f]
  __shared__ unsigned lmask[8];
  __shared__ double sd[4];
  if (tid < 8) lmask[tid] = 0u;

  f32x4 acc[16];
#pragma unroll
  for (int n = 0; n < 16; ++n) acc[n] = (f32x4){0.f, 0.f, 0.f, 0.f};

  // B-slice stage: 16KB = 256 actions x 64B; 4 instrs/wave (16 actions each).
#define STAGE_B(buf, kkv)                                                     \
  {                                                                           \
    _Pragma("unroll") for (int i = 0; i < 4; ++i) {                           \
      const unsigned short* src = Gt +                                        \
          (size_t)(64 * wv + 16 * i + (lane >> 2)) * GT_PITCH +               \
          (kkv) * 32 + (lane & 3) * 8;                                        \
      unsigned short* dst = &Bb[(buf)][64 * wv + 16 * i][0];                  \
      __builtin_amdgcn_global_load_lds(                                       \
          (const __attribute__((address_space(1))) unsigned*)src,             \
          (__attribute__((address_space(3))) unsigned*)dst, 16, 0, 0);        \
    }                                                                         \
  }

  // A loads: 8 dwords (f-run 8g..8g+7 at fixed t), clamp only needed at kk=8.
#define LOAD_A(slot, kkv)                                                     \
  {                                                                           \
    _Pragma("unroll") for (int j = 0; j < 8; ++j) {                           \
      int f = 32 * (kkv) + 8 * g + j;                                         \
      if ((kkv) == 8) f = f > 256 ? 256 : f;                                  \
      va[slot][j] = xs[(size_t)f * T_STEPS + trow];                           \
    }                                                                         \
  }

  float va[2][8];
  // prologue: B(0), A(0), B(1), A(1)  (interleaved issue order matters)
  STAGE_B(0, 0);
  LOAD_A(0, 0);
  STAGE_B(1, 1);
  LOAD_A(1, 1);

#pragma unroll
  for (int kk = 0; kk < 9; ++kk) {
    // pack current A (compiler inserts its own vmcnt for va[kk&1] here;
    // it only forces older (already-needed) retirement)
    const int s = kk & 1;
    const s16x8 af = __builtin_bit_cast(s16x8, (u32x4){
        pack_bf(va[s][1], va[s][0]), pack_bf(va[s][3], va[s][2]),
        pack_bf(va[s][5], va[s][4]), pack_bf(va[s][7], va[s][6])});

    if (kk <= 6) STAGE_B((kk + 2) % 3, kk + 2);
    __builtin_amdgcn_sched_barrier(0);  // pin B-stage before A-loads
    if (kk <= 6) LOAD_A(s, kk + 2);

    // wait until B-buffer kk staged. True younger-issued counts:
    // {32,32,32,32,32,32,32,20,8}; -8 safety margin (over-wait is safe).
    if (kk <= 6)      asm volatile("s_waitcnt vmcnt(24)" ::: "memory");
    else if (kk == 7) asm volatile("s_waitcnt vmcnt(12)" ::: "memory");
    else              asm volatile("s_waitcnt vmcnt(0)"  ::: "memory");
    __builtin_amdgcn_s_barrier();  // all waves' portions staged

    const int buf = kk % 3;
#pragma unroll
    for (int n = 0; n < 16; ++n) {
      const s16x8 bfr = *(const s16x8*)&Bb[buf][16 * n + r16][g * 8];
      acc[n] = __builtin_amdgcn_mfma_f32_16x16x32_bf16(af, bfr, acc[n], 0, 0, 0);
    }
    __builtin_amdgcn_s_barrier();  // done reading buf before it is re-staged
  }
#undef STAGE_B
#undef LOAD_A

  // ---- per-row argmax over 256 actions (row=4g+q, col=16n+r16) ----
  float bv[4]; int bc[4];
#pragma unroll
  for (int q = 0; q < 4; ++q) { bv[q] = acc[0][q]; bc[q] = r16; }
#pragma unroll
  for (int n = 1; n < 16; ++n) {
    const int c = 16 * n + r16;
#pragma unroll
    for (int q = 0; q < 4; ++q)
      if (acc[n][q] > bv[q]) { bv[q] = acc[n][q]; bc[q] = c; }
  }
#pragma unroll
  for (int m = 1; m <= 8; m <<= 1) {
#pragma unroll
    for (int q = 0; q < 4; ++q) {
      const float ov = __shfl_xor(bv[q], m);
      const int   oc = __shfl_xor(bc[q], m);
      if (ov > bv[q] || (ov == bv[q] && oc < bc[q])) { bv[q] = ov; bc[q] = oc; }
    }
  }
  __syncthreads();
  if (r16 == 0) {
#pragma unroll
    for (int q = 0; q < 4; ++q)
      atomicOr(&lmask[bc[q] >> 5], 1u << (bc[q] & 31));
  }
  __syncthreads();
  if (tid < 8) maskp[blockIdx.x * 8 + tid] = lmask[tid];

  // ---- fused sum of x_out^2: contiguous per-block float4 chunk ----
  const float4* xo4 = (const float4*)xo;
  const int base = blockIdx.x * XO_CHUNK;
  double ds = 0.0;
#pragma unroll 4
  for (int i = tid; i < XO_CHUNK; i += 256) {
    const float4 v = xo4[base + i];
    ds += (double)fmaf(v.x, v.x, v.y * v.y) + (double)fmaf(v.z, v.z, v.w * v.w);
  }
#pragma unroll
  for (int off = 32; off; off >>= 1) ds += __shfl_down(ds, off);
  if (lane == 0) sd[wv] = ds;
  __syncthreads();
  if (tid == 0) atomicAdd(Sb, sd[0] + sd[1] + sd[2] + sd[3]);
}

// ---------------------------------------------------------------------------
__global__ __launch_bounds__(256) void k_corr(
    const float* __restrict__ xs, const float* __restrict__ xo,
    const float* __restrict__ G, const unsigned* __restrict__ maskp,
    double* __restrict__ Sc) {
  __shared__ unsigned m8[8];
  const int tid = threadIdx.x;
  if (tid < 8) m8[tid] = 0u;
  __syncthreads();
  unsigned m = 0;
  for (int b = tid >> 3; b < NBLK; b += 32) m |= maskp[b * 8 + (tid & 7)];
  atomicOr(&m8[tid & 7], m);
  __syncthreads();
  const int f = blockIdx.x;
  const int a = tid;
  const bool sel = (m8[a >> 5] >> (a & 31)) & 1u;
  const float gv  = G[f * N_ACT + a];
  const float xsv = xs[f * T_STEPS + a];
  const float xov = xo[f * T_STEPS + a];
  const float gx  = gv * xsv;
  double acc = sel ? (double)(gx * (gx - 2.f * xov)) : 0.0;
#pragma unroll
  for (int off = 32; off; off >>= 1) acc += __shfl_down(acc, off);
  __shared__ double sdc[4];
  if ((tid & 63) == 0) sdc[tid >> 6] = acc;
  __syncthreads();
  if (tid == 0) atomicAdd(Sc, sdc[0] + sdc[1] + sdc[2] + sdc[3]);
}

__global__ void k_final(const double* __restrict__ Sb,
                        const double* __restrict__ Sc,
                        float* __restrict__ out) {
  out[0] = (float)((Sb[0] + Sc[0]) / ((double)F_BINS * (double)T_STEPS));
}

extern "C" void kernel_launch(void* const* d_in, const int* in_sizes, int n_in,
                              void* d_out, int out_size, void* d_ws, size_t ws_size,
                              hipStream_t stream) {
  const float* x_out    = (const float*)d_in[0];
  const float* x_source = (const float*)d_in[1];
  // d_in[2] (x_clean) is dead: argmin_a(clean_sum - proj) == argmax_a proj
  const float* G        = (const float*)d_in[3];

  char* ws = (char*)d_ws;
  double*         Sc    = (double*)ws;
  double*         Sb    = (double*)(ws + 8);
  unsigned*       maskp = (unsigned*)(ws + 16384);
  unsigned short* Gt    = (unsigned short*)(ws + 65536);

  hipMemsetAsync(d_ws, 0, 64, stream);
  k_prep <<<dim3(16, 19), dim3(16, 16), 0, stream>>>(G, Gt);
  k_gemm <<<NBLK, 256, 0, stream>>>(x_source, x_out, Gt, maskp, Sb);
  k_corr <<<F_BINS, 256, 0, stream>>>(x_source, x_out, G, maskp, Sc);
  k_final<<<1, 1, 0, stream>>>(Sb, Sc, (float*)d_out);
}